// Round 6
// baseline (8918.761 us; speedup 1.0000x reference)
//
#include <hip/hip_runtime.h>

// Problem constants
#define Bz 64
#define Nz 64
#define Tz 60
#define Dz 4
#define Hz 64
#define ETz 4
#define Ez 4032   // Nz*(Nz-1)

typedef _Float16 f16x8 __attribute__((ext_vector_type(8)));
typedef float    f32x4 __attribute__((ext_vector_type(4)));
typedef unsigned int u32;
typedef u32      u32x4 __attribute__((ext_vector_type(4)));
typedef unsigned short u16;

__device__ __forceinline__ float ftanh(float x) {
    float e = __expf(2.0f * x);
    return 1.0f - 2.0f * __builtin_amdgcn_rcpf(e + 1.0f);
}
__device__ __forceinline__ float fsig(float x) {
    return __builtin_amdgcn_rcpf(1.0f + __expf(-x));
}
__device__ __forceinline__ u32 pk2(_Float16 a, _Float16 b) {
    u32 ua = (u32)__builtin_bit_cast(u16, a);
    u32 ub = (u32)__builtin_bit_cast(u16, b);
    return ua | (ub << 16);
}

// ---------------------------------------------------------------------------
// Clinical MLPs. Grid 8192 = 64 b x 2 head x 64 jb. 64 threads.
// ---------------------------------------------------------------------------
__global__ __launch_bounds__(64) void k_clinical(
    const float* __restrict__ clin,
    const float* __restrict__ hw1, const float* __restrict__ hb1,
    const float* __restrict__ hw2, const float* __restrict__ hb2,
    const float* __restrict__ hw3, const float* __restrict__ hb3,
    const float* __restrict__ mw1, const float* __restrict__ mb1,
    const float* __restrict__ mw2, const float* __restrict__ mb2,
    const float* __restrict__ mw3, const float* __restrict__ mb3,
    float* __restrict__ hidden, float* __restrict__ clnmsg)
{
    int bi = blockIdx.x;
    int b = bi >> 7, head = (bi >> 6) & 1, jb = bi & 63;
    int tid = threadIdx.x;
    const float* w1 = head ? mw1 : hw1; const float* b1 = head ? mb1 : hb1;
    const float* w2 = head ? mw2 : hw2; const float* b2v = head ? mb2 : hb2;
    const float* w3 = head ? mw3 : hw3; const float* b3 = head ? mb3 : hb3;
    float* outp = head ? clnmsg : hidden;

    __shared__ float sc[16], s1[64], s2[128];
    if (tid < 16) sc[tid] = clin[b * 16 + tid];
    __syncthreads();
    {
        float a = b1[tid];
        #pragma unroll
        for (int c = 0; c < 16; ++c) a = fmaf(sc[c], w1[c * 64 + tid], a);
        s1[tid] = fmaxf(a, 0.f);
    }
    __syncthreads();
    #pragma unroll
    for (int hh = 0; hh < 2; ++hh) {
        int jj = hh * 64 + tid;
        float a = b2v[jj];
        #pragma unroll 8
        for (int c = 0; c < 64; ++c) a = fmaf(s1[c], w2[c * 128 + jj], a);
        s2[jj] = fmaxf(a, 0.f);
    }
    __syncthreads();
    {
        int j = jb * 64 + tid;
        float a = b3[j];
        #pragma unroll 8
        for (int c = 0; c < 128; ++c) a = fmaf(s2[c], w3[c * 4096 + j], a);
        outp[b * 4096 + j] = a;
    }
}

// ---------------------------------------------------------------------------
// msg_w2 [t][k][g] -> split f16 planes in fragment-ready layout:
// plane[((t*8 + n*2 + kt)*64 + L)*8 + j] = w2[t][kt*32+(L>>4)*8+j][n*16+(L&15)]
// ---------------------------------------------------------------------------
__global__ __launch_bounds__(256) void k_wprep(const float* __restrict__ w2,
                                               u16* __restrict__ Whi,
                                               u16* __restrict__ Wlo)
{
    int id = blockIdx.x * 256 + threadIdx.x;   // 16384
    int j = id & 7, L = (id >> 3) & 63, r = id >> 9;
    int kt = r & 1, n = (r >> 1) & 3, t = r >> 3;
    int k = kt * 32 + ((L >> 4) << 3) + j;
    int g = n * 16 + (L & 15);
    float w = w2[(t * 64 + k) * 64 + g];
    _Float16 h = (_Float16)w;
    _Float16 l = (_Float16)((w - (float)h) * 4096.0f);
    Whi[id] = __builtin_bit_cast(u16, h);
    Wlo[id] = __builtin_bit_cast(u16, l);
}

// ---------------------------------------------------------------------------
// x0 = data[:,:,0,:] -> xbuf and out[:,:,0,:]
// ---------------------------------------------------------------------------
__global__ __launch_bounds__(256) void k_init(const float* __restrict__ data,
                                              float* __restrict__ xbuf,
                                              float* __restrict__ out)
{
    int i = blockIdx.x * 256 + threadIdx.x;   // 16384
    int bn = i >> 2, d = i & 3;
    float v = data[bn * (Tz * Dz) + d];
    xbuf[i] = v;
    out[bn * (Tz * Dz) + d] = v;
}

// ---------------------------------------------------------------------------
// Projection, 2 nodes per wave: Hrb[node][t][k] = h@W1r[t]+b1[t];
// Hs[b][t][k][n] = h@W1s[t].  Grid 2048 x 64.
// ---------------------------------------------------------------------------
__global__ __launch_bounds__(64) void k_proj2(
    const float* __restrict__ h, const float* __restrict__ w1,
    const float* __restrict__ b1,
    float* __restrict__ Hrb, float* __restrict__ Hs)
{
    int blk = blockIdx.x;
    int b = blk >> 5;
    int n0 = (blk & 31) * 2, n1 = n0 + 1;
    int l = threadIdx.x;
    __shared__ float s0[64], s1v[64];
    s0[l]  = h[(b * 64 + n0) * 64 + l];
    s1v[l] = h[(b * 64 + n1) * 64 + l];
    __syncthreads();
    #pragma unroll 1
    for (int t = 0; t < 4; ++t) {
        const float* w = w1 + t * 8192;
        float bb = b1[t * 64 + l];
        float ar0 = bb, as0 = 0.f, ar1 = bb, as1 = 0.f;
        #pragma unroll 8
        for (int c = 0; c < 64; ++c) {
            float wr = w[c * 64 + l];
            float wsv = w[(c + 64) * 64 + l];
            float h0 = s0[c], h1 = s1v[c];
            ar0 = fmaf(h0, wr, ar0); as0 = fmaf(h0, wsv, as0);
            ar1 = fmaf(h1, wr, ar1); as1 = fmaf(h1, wsv, as1);
        }
        Hrb[((b * 64 + n0) * 4 + t) * 64 + l] = ar0;
        Hrb[((b * 64 + n1) * 4 + t) * 64 + l] = ar1;
        Hs[((b * 4 + t) * 64 + l) * 64 + n0] = as0;
        Hs[((b * 4 + t) * 64 + l) * 64 + n1] = as1;
    }
}

// ---------------------------------------------------------------------------
// Fused step kernel: edge messages (MFMA split-f16) + agg + GRU + out MLP.
// Grid 4096 blocks (b, rv) x 256 threads (4 waves, wave = m-tile of 16 edges).
// ---------------------------------------------------------------------------
__global__ __launch_bounds__(256, 5) void k_step(
    const float* __restrict__ Hrb, const float* __restrict__ Hs,
    const float* __restrict__ rel_type, const float* __restrict__ b2,
    const u16* __restrict__ Whi, const u16* __restrict__ Wlo,
    const float* __restrict__ cln,
    float* __restrict__ hbuf, float* __restrict__ xbuf,
    const float* __restrict__ irw, const float* __restrict__ irb,
    const float* __restrict__ izw, const float* __restrict__ izb,
    const float* __restrict__ inw, const float* __restrict__ inb,
    const float* __restrict__ hrw, const float* __restrict__ hrbv,
    const float* __restrict__ hnw, const float* __restrict__ hnbv,
    const float* __restrict__ o1w, const float* __restrict__ o1b,
    const float* __restrict__ o2w, const float* __restrict__ o2b,
    const float* __restrict__ o3w, const float* __restrict__ o3b,
    float* __restrict__ out, int tout)
{
    int blk = blockIdx.x;
    int b = blk >> 6, rv = blk & 63;
    int tid = threadIdx.x;
    int w = tid >> 6, L = tid & 63;
    int kg = L >> 4, el = L & 15;
    int e = w * 16 + el;                       // edge index 0..63 (63 = dummy)

    __shared__ __align__(16) _Float16 ZaH[4][16][64];
    __shared__ __align__(16) _Float16 ZaL[4][16][64];
    __shared__ __align__(16) float srt[256];   // [t][e]
    __shared__ float sRed[4][64];
    __shared__ float sA[64], sH[64], sP[64];

    // stage rel_type transposed, pad edge 63 with 0
    {
        const float* rbase = rel_type + (b * Ez + rv * 63) * 4;
        float v = (tid < 252) ? rbase[tid] : 0.f;
        srt[(tid & 3) * 64 + (tid >> 2)] = v;
    }
    __syncthreads();

    int snd = (e < 63) ? (e + (e >= rv ? 1 : 0)) : 0;
    int em = el & 7;
    float pacc0 = 0.f, pacc1 = 0.f, pacc2 = 0.f, pacc3 = 0.f;

    #pragma unroll 1
    for (int t = 0; t < 4; ++t) {
        // ---- z-phase: lane computes k = kg*16 + j for its edge e ----
        const float* hrp = Hrb + blk * 256 + t * 64 + kg * 16;
        const float* hsp = Hs + (b * 4 + t) * 4096 + kg * 1024 + snd;
        float zv[16];
        #pragma unroll
        for (int j = 0; j < 16; ++j) zv[j] = hrp[j] + hsp[j * 64];
        #pragma unroll
        for (int j = 0; j < 16; ++j) zv[j] = ftanh(zv[j]);

        // split + pack into wave-local swizzled LDS planes
        #pragma unroll
        for (int p = 0; p < 2; ++p) {
            u32 hi[4], lo[4];
            #pragma unroll
            for (int q = 0; q < 4; ++q) {
                float a = zv[p * 8 + 2 * q], c = zv[p * 8 + 2 * q + 1];
                _Float16 ha = (_Float16)a, hc = (_Float16)c;
                _Float16 la = (_Float16)((a - (float)ha) * 4096.0f);
                _Float16 lc = (_Float16)((c - (float)hc) * 4096.0f);
                hi[q] = pk2(ha, hc);
                lo[q] = pk2(la, lc);
            }
            int cp = (2 * kg + p) ^ em;
            u32x4 vh = {hi[0], hi[1], hi[2], hi[3]};
            u32x4 vl = {lo[0], lo[1], lo[2], lo[3]};
            *(u32x4*)&ZaH[w][el][cp * 8] = vh;
            *(u32x4*)&ZaL[w][el][cp * 8] = vl;
        }

        // ---- A fragments (direct b128 reads, no unpack) ----
        f16x8 Ah[2], Al[2];
        #pragma unroll
        for (int kt = 0; kt < 2; ++kt) {
            int cp = (kt * 4 + kg) ^ em;
            Ah[kt] = *(const f16x8*)&ZaH[w][el][cp * 8];
            Al[kt] = *(const f16x8*)&ZaL[w][el][cp * 8];
        }

        f32x4 rt4 = *(const f32x4*)&srt[t * 64 + w * 16 + kg * 4];

        // ---- N-tiles ----
        #pragma unroll
        for (int n = 0; n < 4; ++n) {
            const u16* wb = Whi + ((t * 8 + n * 2) * 64 + L) * 8;
            const u16* wl = Wlo + ((t * 8 + n * 2) * 64 + L) * 8;
            f16x8 Bh0 = *(const f16x8*)wb;
            f16x8 Bh1 = *(const f16x8*)(wb + 512);
            f16x8 Bl0 = *(const f16x8*)wl;
            f16x8 Bl1 = *(const f16x8*)(wl + 512);
            f32x4 hh = {0.f, 0.f, 0.f, 0.f};
            f32x4 cc = {0.f, 0.f, 0.f, 0.f};
            hh = __builtin_amdgcn_mfma_f32_16x16x32_f16(Ah[0], Bh0, hh, 0, 0, 0);
            hh = __builtin_amdgcn_mfma_f32_16x16x32_f16(Ah[1], Bh1, hh, 0, 0, 0);
            cc = __builtin_amdgcn_mfma_f32_16x16x32_f16(Ah[0], Bl0, cc, 0, 0, 0);
            cc = __builtin_amdgcn_mfma_f32_16x16x32_f16(Al[0], Bh0, cc, 0, 0, 0);
            cc = __builtin_amdgcn_mfma_f32_16x16x32_f16(Ah[1], Bl1, cc, 0, 0, 0);
            cc = __builtin_amdgcn_mfma_f32_16x16x32_f16(Al[1], Bh1, cc, 0, 0, 0);
            float b2n = b2[t * 64 + n * 16 + el];
            float acc = 0.f;
            #pragma unroll
            for (int r = 0; r < 4; ++r) {
                float v = fmaf(cc[r], (1.0f / 4096.0f), hh[r]) + b2n;
                acc = fmaf(ftanh(v), rt4[r], acc);
            }
            if (n == 0) pacc0 += acc;
            else if (n == 1) pacc1 += acc;
            else if (n == 2) pacc2 += acc;
            else pacc3 += acc;
        }
    }

    // reduce over the 4 lane-groups (edges within the m-tile)
    pacc0 += __shfl_xor(pacc0, 16); pacc0 += __shfl_xor(pacc0, 32);
    pacc1 += __shfl_xor(pacc1, 16); pacc1 += __shfl_xor(pacc1, 32);
    pacc2 += __shfl_xor(pacc2, 16); pacc2 += __shfl_xor(pacc2, 32);
    pacc3 += __shfl_xor(pacc3, 16); pacc3 += __shfl_xor(pacc3, 32);
    if (L < 16) {
        sRed[w][0 * 16 + L] = pacc0;
        sRed[w][1 * 16 + L] = pacc1;
        sRed[w][2 * 16 + L] = pacc2;
        sRed[w][3 * 16 + L] = pacc3;
    }
    __syncthreads();
    if (tid < 64) {
        float av = (sRed[0][tid] + sRed[1][tid] + sRed[2][tid] + sRed[3][tid]) * 0.0625f;
        sA[tid] = av + cln[blk * 64 + tid];
    }
    __syncthreads();

    // ---- node phase on wave 0 ----
    if (w == 0) {
        float h_old = hbuf[blk * 64 + L];
        float x0 = xbuf[blk * 4 + 0], x1 = xbuf[blk * 4 + 1];
        float x2 = xbuf[blk * 4 + 2], x3 = xbuf[blk * 4 + 3];

        float hra = hrbv[L], hna = hnbv[L];
        #pragma unroll 8
        for (int k = 0; k < 64; ++k) {
            float av = sA[k];
            hra = fmaf(av, hrw[k * 64 + L], hra);
            hna = fmaf(av, hnw[k * 64 + L], hna);
        }
        float xr = irb[L], xz = izb[L], xn = inb[L];
        xr = fmaf(x0, irw[L], xr); xr = fmaf(x1, irw[64 + L], xr);
        xr = fmaf(x2, irw[128 + L], xr); xr = fmaf(x3, irw[192 + L], xr);
        xz = fmaf(x0, izw[L], xz); xz = fmaf(x1, izw[64 + L], xz);
        xz = fmaf(x2, izw[128 + L], xz); xz = fmaf(x3, izw[192 + L], xz);
        xn = fmaf(x0, inw[L], xn); xn = fmaf(x1, inw[64 + L], xn);
        xn = fmaf(x2, inw[128 + L], xn); xn = fmaf(x3, inw[192 + L], xn);

        float r = fsig(xr + hra);
        float z = fsig(xz + hra);
        float nn = ftanh(xn + r * hna);
        float hnew = (1.f - z) * nn + z * h_old;
        hbuf[blk * 64 + L] = hnew;
        sH[L] = hnew;

        float p = o1b[L];
        #pragma unroll 8
        for (int k = 0; k < 64; ++k) p = fmaf(sH[k], o1w[k * 64 + L], p);
        p = fmaxf(p, 0.f);
        sP[L] = p;
        float q = o2b[L];
        #pragma unroll 8
        for (int k = 0; k < 64; ++k) q = fmaf(sP[k], o2w[k * 64 + L], q);
        q = fmaxf(q, 0.f);
        sP[L] = q;
        if (L < 4) {
            float xv = (L == 0) ? x0 : (L == 1) ? x1 : (L == 2) ? x2 : x3;
            float pr = xv + o3b[L];
            #pragma unroll 8
            for (int k = 0; k < 64; ++k) pr = fmaf(sP[k], o3w[k * 4 + L], pr);
            out[(blk * Tz + tout) * 4 + L] = pr;
            xbuf[blk * 4 + L] = pr;
        }
    }
}

// ---------------------------------------------------------------------------
extern "C" void kernel_launch(void* const* d_in, const int* in_sizes, int n_in,
                              void* d_out, int out_size, void* d_ws, size_t ws_size,
                              hipStream_t stream)
{
    const float* data     = (const float*)d_in[0];
    const float* rel_type = (const float*)d_in[1];
    const float* clinical = (const float*)d_in[4];
    const float* msg_w1 = (const float*)d_in[5];
    const float* msg_b1 = (const float*)d_in[6];
    const float* msg_w2 = (const float*)d_in[7];
    const float* msg_b2 = (const float*)d_in[8];
    const float* chw1 = (const float*)d_in[9];
    const float* chb1 = (const float*)d_in[10];
    const float* chw2 = (const float*)d_in[11];
    const float* chb2 = (const float*)d_in[12];
    const float* chw3 = (const float*)d_in[13];
    const float* chb3 = (const float*)d_in[14];
    const float* cmw1 = (const float*)d_in[15];
    const float* cmb1 = (const float*)d_in[16];
    const float* cmw2 = (const float*)d_in[17];
    const float* cmb2 = (const float*)d_in[18];
    const float* cmw3 = (const float*)d_in[19];
    const float* cmb3 = (const float*)d_in[20];
    const float* irw = (const float*)d_in[21];
    const float* irb = (const float*)d_in[22];
    const float* izw = (const float*)d_in[23];
    const float* izb = (const float*)d_in[24];
    const float* inw = (const float*)d_in[25];
    const float* inb = (const float*)d_in[26];
    const float* hrw = (const float*)d_in[27];
    const float* hrb = (const float*)d_in[28];
    const float* hnw = (const float*)d_in[29];
    const float* hnb = (const float*)d_in[30];
    const float* o1w = (const float*)d_in[31];
    const float* o1b = (const float*)d_in[32];
    const float* o2w = (const float*)d_in[33];
    const float* o2b = (const float*)d_in[34];
    const float* o3w = (const float*)d_in[35];
    const float* o3b = (const float*)d_in[36];

    float* ws   = (float*)d_ws;
    float* hbuf = ws;                   // 262144
    float* cln  = ws + 262144;          // 262144
    float* Hrb  = ws + 524288;          // 1048576
    float* Hs   = ws + 1572864;         // 1048576
    float* xbuf = ws + 2621440;         // 16384
    u16*   Whi  = (u16*)(ws + 2637824); // 16384 u16 (8192 f32 slots)
    u16*   Wlo  = (u16*)(ws + 2646016); // 16384 u16
    float* out  = (float*)d_out;

    k_clinical<<<dim3(8192), dim3(64), 0, stream>>>(
        clinical, chw1, chb1, chw2, chb2, chw3, chb3,
        cmw1, cmb1, cmw2, cmb2, cmw3, cmb3, hbuf, cln);
    k_wprep<<<dim3(64), dim3(256), 0, stream>>>(msg_w2, Whi, Wlo);
    k_init<<<dim3(64), dim3(256), 0, stream>>>(data, xbuf, out);
    k_proj2<<<dim3(2048), dim3(64), 0, stream>>>(hbuf, msg_w1, msg_b1, Hrb, Hs);

    for (int t = 1; t < Tz; ++t) {
        k_step<<<dim3(Bz * Nz), dim3(256), 0, stream>>>(
            Hrb, Hs, rel_type, msg_b2, Whi, Wlo, cln, hbuf, xbuf,
            irw, irb, izw, izb, inw, inb,
            hrw, hrb, hnw, hnb,
            o1w, o1b, o2w, o2b, o3w, o3b, out, t);
        if (t < Tz - 1)
            k_proj2<<<dim3(2048), dim3(64), 0, stream>>>(hbuf, msg_w1, msg_b1, Hrb, Hs);
    }
}

// Round 9
// 7408.455 us; speedup vs baseline: 1.2039x; 1.2039x over previous
//
#include <hip/hip_runtime.h>

// Problem constants
#define Bz 64
#define Nz 64
#define Tz 60
#define Dz 4
#define Hz 64
#define ETz 4
#define Ez 4032   // Nz*(Nz-1)

typedef _Float16 f16x8 __attribute__((ext_vector_type(8)));
typedef float    f32x4 __attribute__((ext_vector_type(4)));
typedef unsigned int u32;
typedef u32      u32x4 __attribute__((ext_vector_type(4)));
typedef unsigned short u16;

__device__ __forceinline__ float ftanh(float x) {
    float e = __expf(2.0f * x);
    return 1.0f - 2.0f * __builtin_amdgcn_rcpf(e + 1.0f);
}
__device__ __forceinline__ float fsig(float x) {
    return __builtin_amdgcn_rcpf(1.0f + __expf(-x));
}
__device__ __forceinline__ u32 pk2(_Float16 a, _Float16 b) {
    u32 ua = (u32)__builtin_bit_cast(u16, a);
    u32 ub = (u32)__builtin_bit_cast(u16, b);
    return ua | (ub << 16);
}

// ---------------------------------------------------------------------------
// Clinical MLPs. Grid 8192 = 64 b x 2 head x 64 jb. 64 threads.
// ---------------------------------------------------------------------------
__global__ __launch_bounds__(64) void k_clinical(
    const float* __restrict__ clin,
    const float* __restrict__ hw1, const float* __restrict__ hb1,
    const float* __restrict__ hw2, const float* __restrict__ hb2,
    const float* __restrict__ hw3, const float* __restrict__ hb3,
    const float* __restrict__ mw1, const float* __restrict__ mb1,
    const float* __restrict__ mw2, const float* __restrict__ mb2,
    const float* __restrict__ mw3, const float* __restrict__ mb3,
    float* __restrict__ hidden, float* __restrict__ clnmsg)
{
    int bi = blockIdx.x;
    int b = bi >> 7, head = (bi >> 6) & 1, jb = bi & 63;
    int tid = threadIdx.x;
    const float* w1 = head ? mw1 : hw1; const float* b1 = head ? mb1 : hb1;
    const float* w2 = head ? mw2 : hw2; const float* b2v = head ? mb2 : hb2;
    const float* w3 = head ? mw3 : hw3; const float* b3 = head ? mb3 : hb3;
    float* outp = head ? clnmsg : hidden;

    __shared__ float sc[16], s1[64], s2[128];
    if (tid < 16) sc[tid] = clin[b * 16 + tid];
    __syncthreads();
    {
        float a = b1[tid];
        #pragma unroll
        for (int c = 0; c < 16; ++c) a = fmaf(sc[c], w1[c * 64 + tid], a);
        s1[tid] = fmaxf(a, 0.f);
    }
    __syncthreads();
    #pragma unroll
    for (int hh = 0; hh < 2; ++hh) {
        int jj = hh * 64 + tid;
        float a = b2v[jj];
        #pragma unroll 8
        for (int c = 0; c < 64; ++c) a = fmaf(s1[c], w2[c * 128 + jj], a);
        s2[jj] = fmaxf(a, 0.f);
    }
    __syncthreads();
    {
        int j = jb * 64 + tid;
        float a = b3[j];
        #pragma unroll 8
        for (int c = 0; c < 128; ++c) a = fmaf(s2[c], w3[c * 4096 + j], a);
        outp[b * 4096 + j] = a;
    }
}

// ---------------------------------------------------------------------------
// msg_w2 [t][k][g] -> split f16 planes in fragment-ready layout:
// plane[((t*8 + n*2 + kt)*64 + L)*8 + j] = w2[t][kt*32+(L>>4)*8+j][n*16+(L&15)]
// ---------------------------------------------------------------------------
__global__ __launch_bounds__(256) void k_wprep(const float* __restrict__ w2,
                                               u16* __restrict__ Whi,
                                               u16* __restrict__ Wlo)
{
    int id = blockIdx.x * 256 + threadIdx.x;   // 16384
    int j = id & 7, L = (id >> 3) & 63, r = id >> 9;
    int kt = r & 1, n = (r >> 1) & 3, t = r >> 3;
    int k = kt * 32 + ((L >> 4) << 3) + j;
    int g = n * 16 + (L & 15);
    float w = w2[(t * 64 + k) * 64 + g];
    _Float16 h = (_Float16)w;
    _Float16 l = (_Float16)((w - (float)h) * 4096.0f);
    Whi[id] = __builtin_bit_cast(u16, h);
    Wlo[id] = __builtin_bit_cast(u16, l);
}

// ---------------------------------------------------------------------------
// x0 = data[:,:,0,:] -> xbuf and out[:,:,0,:]
// ---------------------------------------------------------------------------
__global__ __launch_bounds__(256) void k_init(const float* __restrict__ data,
                                              float* __restrict__ xbuf,
                                              float* __restrict__ out)
{
    int i = blockIdx.x * 256 + threadIdx.x;   // 16384
    int bn = i >> 2, d = i & 3;
    float v = data[bn * (Tz * Dz) + d];
    xbuf[i] = v;
    out[bn * (Tz * Dz) + d] = v;
}

// ---------------------------------------------------------------------------
// Projection, 2 nodes per wave: Hrb[node][t][k] = h@W1r[t]+b1[t];
// Hs[b][t][k][n] = h@W1s[t].  Grid 2048 x 64.
// ---------------------------------------------------------------------------
__global__ __launch_bounds__(64) void k_proj2(
    const float* __restrict__ h, const float* __restrict__ w1,
    const float* __restrict__ b1,
    float* __restrict__ Hrb, float* __restrict__ Hs)
{
    int blk = blockIdx.x;
    int b = blk >> 5;
    int n0 = (blk & 31) * 2, n1 = n0 + 1;
    int l = threadIdx.x;
    __shared__ float s0[64], s1v[64];
    s0[l]  = h[(b * 64 + n0) * 64 + l];
    s1v[l] = h[(b * 64 + n1) * 64 + l];
    __syncthreads();
    #pragma unroll 1
    for (int t = 0; t < 4; ++t) {
        const float* w = w1 + t * 8192;
        float bb = b1[t * 64 + l];
        float ar0 = bb, as0 = 0.f, ar1 = bb, as1 = 0.f;
        #pragma unroll 8
        for (int c = 0; c < 64; ++c) {
            float wr = w[c * 64 + l];
            float wsv = w[(c + 64) * 64 + l];
            float h0 = s0[c], h1 = s1v[c];
            ar0 = fmaf(h0, wr, ar0); as0 = fmaf(h0, wsv, as0);
            ar1 = fmaf(h1, wr, ar1); as1 = fmaf(h1, wsv, as1);
        }
        Hrb[((b * 64 + n0) * 4 + t) * 64 + l] = ar0;
        Hrb[((b * 64 + n1) * 4 + t) * 64 + l] = ar1;
        Hs[((b * 4 + t) * 64 + l) * 64 + n0] = as0;
        Hs[((b * 4 + t) * 64 + l) * 64 + n1] = as1;
    }
}

// ---------------------------------------------------------------------------
// Fused step kernel v2: wave = edge-type t (B frags in registers, loaded once),
// 2 receivers per block (8 m-tiles per wave -> 192 MFMA per 256B of B loads).
// Grid 2048 blocks (b, rv-pair) x 256 threads.
// ---------------------------------------------------------------------------
#define RV_TILES(RVS, PACC)                                                    \
    {                                                                          \
        const int rv = n0 + (RVS);                                             \
        _Pragma("unroll 2")                                                    \
        for (int m = 0; m < 4; ++m) {                                          \
            int e = m * 16 + el;                                               \
            int snd = (e < 63) ? (e + (e >= rv ? 1 : 0)) : 0;                  \
            const float* hs = Hs + (b * 4 + w) * 4096 + kg * 1024 + snd;       \
            float zv[16];                                                      \
            _Pragma("unroll")                                                  \
            for (int j = 0; j < 16; ++j)                                       \
                zv[j] = sHr[(RVS) * 256 + w * 64 + kg * 16 + j] + hs[j * 64];  \
            _Pragma("unroll")                                                  \
            for (int j = 0; j < 16; ++j) zv[j] = ftanh(zv[j]);                 \
            _Pragma("unroll")                                                  \
            for (int p = 0; p < 2; ++p) {                                      \
                u32 hi[4], lo[4];                                              \
                _Pragma("unroll")                                              \
                for (int q = 0; q < 4; ++q) {                                  \
                    float a = zv[p * 8 + 2 * q], c = zv[p * 8 + 2 * q + 1];    \
                    _Float16 ha = (_Float16)a, hc = (_Float16)c;               \
                    _Float16 la = (_Float16)((a - (float)ha) * 4096.0f);       \
                    _Float16 lc = (_Float16)((c - (float)hc) * 4096.0f);       \
                    hi[q] = pk2(ha, hc);                                       \
                    lo[q] = pk2(la, lc);                                       \
                }                                                              \
                int cp = (2 * kg + p) ^ em;                                    \
                u32x4 vh = {hi[0], hi[1], hi[2], hi[3]};                       \
                u32x4 vl = {lo[0], lo[1], lo[2], lo[3]};                       \
                *(u32x4*)&ZaH[w][el][cp * 8] = vh;                             \
                *(u32x4*)&ZaL[w][el][cp * 8] = vl;                             \
            }                                                                  \
            f16x8 Ah[2], Al[2];                                                \
            _Pragma("unroll")                                                  \
            for (int kt = 0; kt < 2; ++kt) {                                   \
                int cp = (kt * 4 + kg) ^ em;                                   \
                Ah[kt] = *(const f16x8*)&ZaH[w][el][cp * 8];                   \
                Al[kt] = *(const f16x8*)&ZaL[w][el][cp * 8];                   \
            }                                                                  \
            f32x4 rt4 = *(const f32x4*)&srt[(RVS) * 256 + w * 64 + m * 16 + kg * 4]; \
            _Pragma("unroll")                                                  \
            for (int n = 0; n < 4; ++n) {                                      \
                f32x4 hh = {0.f, 0.f, 0.f, 0.f};                               \
                f32x4 cc = {0.f, 0.f, 0.f, 0.f};                               \
                hh = __builtin_amdgcn_mfma_f32_16x16x32_f16(Ah[0], Bh[n*2+0], hh, 0, 0, 0); \
                hh = __builtin_amdgcn_mfma_f32_16x16x32_f16(Ah[1], Bh[n*2+1], hh, 0, 0, 0); \
                cc = __builtin_amdgcn_mfma_f32_16x16x32_f16(Ah[0], Bl[n*2+0], cc, 0, 0, 0); \
                cc = __builtin_amdgcn_mfma_f32_16x16x32_f16(Al[0], Bh[n*2+0], cc, 0, 0, 0); \
                cc = __builtin_amdgcn_mfma_f32_16x16x32_f16(Ah[1], Bl[n*2+1], cc, 0, 0, 0); \
                cc = __builtin_amdgcn_mfma_f32_16x16x32_f16(Al[1], Bh[n*2+1], cc, 0, 0, 0); \
                float acc = 0.f;                                               \
                _Pragma("unroll")                                              \
                for (int r = 0; r < 4; ++r) {                                  \
                    float v = fmaf(cc[r], (1.0f / 4096.0f), hh[r]) + b2n[n];   \
                    acc = fmaf(ftanh(v), rt4[r], acc);                         \
                }                                                              \
                PACC[n] += acc;                                                \
            }                                                                  \
        }                                                                      \
    }

__global__ __launch_bounds__(256, 3) void k_step(
    const float* __restrict__ Hrb, const float* __restrict__ Hs,
    const float* __restrict__ rel_type, const float* __restrict__ b2,
    const u16* __restrict__ Whi, const u16* __restrict__ Wlo,
    const float* __restrict__ cln,
    float* __restrict__ hbuf, float* __restrict__ xbuf,
    const float* __restrict__ irw, const float* __restrict__ irb,
    const float* __restrict__ izw, const float* __restrict__ izb,
    const float* __restrict__ inw, const float* __restrict__ inb,
    const float* __restrict__ hrw, const float* __restrict__ hrbv,
    const float* __restrict__ hnw, const float* __restrict__ hnbv,
    const float* __restrict__ o1w, const float* __restrict__ o1b,
    const float* __restrict__ o2w, const float* __restrict__ o2b,
    const float* __restrict__ o3w, const float* __restrict__ o3b,
    float* __restrict__ out, int tout)
{
    int blk = blockIdx.x;
    int b = blk >> 5;
    int n0 = (blk & 31) * 2;                   // receivers n0, n0+1
    int tid = threadIdx.x;
    int w = tid >> 6, L = tid & 63;            // wave w = edge-type t
    int kg = L >> 4, el = L & 15;
    int em = el & 7;

    __shared__ __align__(16) _Float16 ZaH[4][16][64];
    __shared__ __align__(16) _Float16 ZaL[4][16][64];
    __shared__ __align__(16) float srt[512];   // [rvs][t][e]
    __shared__ __align__(16) float sHr[512];   // [rvs][t][k]
    __shared__ float sRed[4][2][64];
    __shared__ float sA[128], sH[128], sP[128];

    // stage rel_type (transposed, pad e=63 with 0) and Hrb for both receivers
    #pragma unroll
    for (int it = 0; it < 2; ++it) {
        int idx = it * 256 + tid;              // 0..511
        int rvs = idx >> 8, r = idx & 255;
        float v = 0.f;
        if (r < 252) v = rel_type[(b * Ez + (n0 + rvs) * 63) * 4 + r];
        srt[rvs * 256 + (r & 3) * 64 + (r >> 2)] = v;
        sHr[idx] = Hrb[(b * 64 + n0) * 256 + idx];
    }
    __syncthreads();

    // B fragments for this wave's t (= w), held in registers for all 8 m-tiles
    f16x8 Bh[8], Bl[8];
    #pragma unroll
    for (int nk = 0; nk < 8; ++nk) {
        Bh[nk] = *(const f16x8*)(Whi + ((w * 8 + nk) * 64 + L) * 8);
        Bl[nk] = *(const f16x8*)(Wlo + ((w * 8 + nk) * 64 + L) * 8);
    }
    float b2n[4];
    #pragma unroll
    for (int n = 0; n < 4; ++n) b2n[n] = b2[w * 64 + n * 16 + el];

    float pA[4] = {0.f, 0.f, 0.f, 0.f};
    float pB[4] = {0.f, 0.f, 0.f, 0.f};
    RV_TILES(0, pA)
    RV_TILES(1, pB)

    // reduce over kg groups (edges) within the wave
    #pragma unroll
    for (int n = 0; n < 4; ++n) {
        pA[n] += __shfl_xor(pA[n], 16); pA[n] += __shfl_xor(pA[n], 32);
        pB[n] += __shfl_xor(pB[n], 16); pB[n] += __shfl_xor(pB[n], 32);
    }
    if (L < 16) {
        #pragma unroll
        for (int n = 0; n < 4; ++n) {
            sRed[w][0][n * 16 + L] = pA[n];
            sRed[w][1][n * 16 + L] = pB[n];
        }
    }
    __syncthreads();
    if (tid < 128) {                            // sum over t (= waves)
        int rvs = tid >> 6, ch = tid & 63;
        float av = (sRed[0][rvs][ch] + sRed[1][rvs][ch] +
                    sRed[2][rvs][ch] + sRed[3][rvs][ch]) * 0.0625f;
        sA[rvs * 64 + ch] = av + cln[(b * 64 + n0 + rvs) * 64 + ch];
    }
    __syncthreads();

    // ---- node phase: wave 0 -> node n0, wave 1 -> node n0+1 ----
    if (w < 2) {
        int node = b * 64 + n0 + w;
        const float* sAp = sA + w * 64;
        float* sHp = sH + w * 64;
        float* sPp = sP + w * 64;

        float h_old = hbuf[node * 64 + L];
        float x0 = xbuf[node * 4 + 0], x1 = xbuf[node * 4 + 1];
        float x2 = xbuf[node * 4 + 2], x3 = xbuf[node * 4 + 3];

        float hra = hrbv[L], hna = hnbv[L];
        #pragma unroll 8
        for (int k = 0; k < 64; ++k) {
            float av = sAp[k];
            hra = fmaf(av, hrw[k * 64 + L], hra);
            hna = fmaf(av, hnw[k * 64 + L], hna);
        }
        float xr = irb[L], xz = izb[L], xn = inb[L];
        xr = fmaf(x0, irw[L], xr); xr = fmaf(x1, irw[64 + L], xr);
        xr = fmaf(x2, irw[128 + L], xr); xr = fmaf(x3, irw[192 + L], xr);
        xz = fmaf(x0, izw[L], xz); xz = fmaf(x1, izw[64 + L], xz);
        xz = fmaf(x2, izw[128 + L], xz); xz = fmaf(x3, izw[192 + L], xz);
        xn = fmaf(x0, inw[L], xn); xn = fmaf(x1, inw[64 + L], xn);
        xn = fmaf(x2, inw[128 + L], xn); xn = fmaf(x3, inw[192 + L], xn);

        float r = fsig(xr + hra);
        float z = fsig(xz + hra);
        float nn = ftanh(xn + r * hna);
        float hnew = (1.f - z) * nn + z * h_old;
        hbuf[node * 64 + L] = hnew;
        sHp[L] = hnew;

        float p = o1b[L];
        #pragma unroll 8
        for (int k = 0; k < 64; ++k) p = fmaf(sHp[k], o1w[k * 64 + L], p);
        p = fmaxf(p, 0.f);
        sPp[L] = p;
        float q = o2b[L];
        #pragma unroll 8
        for (int k = 0; k < 64; ++k) q = fmaf(sPp[k], o2w[k * 64 + L], q);
        q = fmaxf(q, 0.f);
        sPp[L] = q;
        if (L < 4) {
            float xv = (L == 0) ? x0 : (L == 1) ? x1 : (L == 2) ? x2 : x3;
            float pr = xv + o3b[L];
            #pragma unroll 8
            for (int k = 0; k < 64; ++k) pr = fmaf(sPp[k], o3w[k * 4 + L], pr);
            out[(node * Tz + tout) * 4 + L] = pr;
            xbuf[node * 4 + L] = pr;
        }
    }
}

// ---------------------------------------------------------------------------
extern "C" void kernel_launch(void* const* d_in, const int* in_sizes, int n_in,
                              void* d_out, int out_size, void* d_ws, size_t ws_size,
                              hipStream_t stream)
{
    const float* data     = (const float*)d_in[0];
    const float* rel_type = (const float*)d_in[1];
    const float* clinical = (const float*)d_in[4];
    const float* msg_w1 = (const float*)d_in[5];
    const float* msg_b1 = (const float*)d_in[6];
    const float* msg_w2 = (const float*)d_in[7];
    const float* msg_b2 = (const float*)d_in[8];
    const float* chw1 = (const float*)d_in[9];
    const float* chb1 = (const float*)d_in[10];
    const float* chw2 = (const float*)d_in[11];
    const float* chb2 = (const float*)d_in[12];
    const float* chw3 = (const float*)d_in[13];
    const float* chb3 = (const float*)d_in[14];
    const float* cmw1 = (const float*)d_in[15];
    const float* cmb1 = (const float*)d_in[16];
    const float* cmw2 = (const float*)d_in[17];
    const float* cmb2 = (const float*)d_in[18];
    const float* cmw3 = (const float*)d_in[19];
    const float* cmb3 = (const float*)d_in[20];
    const float* irw = (const float*)d_in[21];
    const float* irb = (const float*)d_in[22];
    const float* izw = (const float*)d_in[23];
    const float* izb = (const float*)d_in[24];
    const float* inw = (const float*)d_in[25];
    const float* inb = (const float*)d_in[26];
    const float* hrw = (const float*)d_in[27];
    const float* hrb = (const float*)d_in[28];
    const float* hnw = (const float*)d_in[29];
    const float* hnb = (const float*)d_in[30];
    const float* o1w = (const float*)d_in[31];
    const float* o1b = (const float*)d_in[32];
    const float* o2w = (const float*)d_in[33];
    const float* o2b = (const float*)d_in[34];
    const float* o3w = (const float*)d_in[35];
    const float* o3b = (const float*)d_in[36];

    float* ws   = (float*)d_ws;
    float* hbuf = ws;                   // 262144
    float* cln  = ws + 262144;          // 262144
    float* Hrb  = ws + 524288;          // 1048576
    float* Hs   = ws + 1572864;         // 1048576
    float* xbuf = ws + 2621440;         // 16384
    u16*   Whi  = (u16*)(ws + 2637824); // 16384 u16 (8192 f32 slots)
    u16*   Wlo  = (u16*)(ws + 2646016); // 16384 u16
    float* out  = (float*)d_out;

    k_clinical<<<dim3(8192), dim3(64), 0, stream>>>(
        clinical, chw1, chb1, chw2, chb2, chw3, chb3,
        cmw1, cmb1, cmw2, cmb2, cmw3, cmb3, hbuf, cln);
    k_wprep<<<dim3(64), dim3(256), 0, stream>>>(msg_w2, Whi, Wlo);
    k_init<<<dim3(64), dim3(256), 0, stream>>>(data, xbuf, out);
    k_proj2<<<dim3(2048), dim3(64), 0, stream>>>(hbuf, msg_w1, msg_b1, Hrb, Hs);

    for (int t = 1; t < Tz; ++t) {
        k_step<<<dim3(2048), dim3(256), 0, stream>>>(
            Hrb, Hs, rel_type, msg_b2, Whi, Wlo, cln, hbuf, xbuf,
            irw, irb, izw, izb, inw, inb,
            hrw, hrb, hnw, hnb,
            o1w, o1b, o2w, o2b, o3w, o3b, out, t);
        if (t < Tz - 1)
            k_proj2<<<dim3(2048), dim3(64), 0, stream>>>(hbuf, msg_w1, msg_b1, Hrb, Hs);
    }
}